// Round 6
// baseline (90.200 us; speedup 1.0000x reference)
//
#include <hip/hip_runtime.h>

#define BINS 10
#define NTHREADS 256
#define LOG2E 1.44269504f
#define KBIAS 1024.0f
#define TILE_ELEMS (NTHREADS * 64)   // 16384 elements per block-tile
#define ROUNDS 8                     // 8 rounds x 8 elems/thread = 64/thread

// ---------------------------------------------------------------------------
// GHM loss. R6: block-contiguous tiles + bias-packed staircase.
//   y = t ? x : -x ;  E = exp2(-y*log2e) ;  bce2 = log2(1+E)  [*ln2 deferred]
//   staircase: g >= b/10  <=>  y <= c_b = ln((10-b)/b)
//   T'[b] += (y<=c_b) ? (bce2 + 1024) : 0   -- count folded into sum:
//   per-thread decode c = floor(T'/1024) (exact: sum < 557 < 1024, c <= 64).
// Lessons: R3 no per-elem LDS; R4 no ballot; R5 addr math ~= staircase cost ->
// contiguous tile + offset:16 folding + one increment per stream per round.
// ---------------------------------------------------------------------------

// c_b = ln((10-b)/b), b=1..9
#define GHM_C1  2.19722458f
#define GHM_C2  1.38629436f
#define GHM_C3  0.84729786f
#define GHM_C4  0.40546511f
#define GHM_C5  0.0f
#define GHM_C6 -0.40546511f
#define GHM_C7 -0.84729786f
#define GHM_C8 -1.38629436f
#define GHM_C9 -2.19722458f

__device__ __forceinline__ float wave_reduce_add(float v) {
#pragma unroll
    for (int off = 32; off > 0; off >>= 1) v += __shfl_down(v, off, 64);
    return v;
}
__device__ __forceinline__ unsigned int wave_reduce_addu(unsigned int v) {
#pragma unroll
    for (int off = 32; off > 0; off >>= 1) v += __shfl_down((int)v, off, 64);
    return v;
}

__global__ __launch_bounds__(NTHREADS, 6) void ghm_pass1(
    const float* __restrict__ pred, const int* __restrict__ target,
    float* __restrict__ g_T,            // [BINS] cumulative bce2 sums
    unsigned int* __restrict__ g_C,     // [BINS] cumulative counts (1..9 used)
    int n)
{
    float T0 = 0.f;      // sum of bce2 over all elements (bin-0 cumulative)
    float Tb[9];         // biased staircase sums, b=1..9
#pragma unroll
    for (int b = 0; b < 9; ++b) Tb[b] = 0.f;

    const int tid    = threadIdx.x;
    const int ntiles = n / TILE_ELEMS;

#define GHM_ELEM(x_, t_)                                                     \
    {                                                                        \
        const float x = (x_);                                                \
        const float y = ((t_) != 0) ? x : -x;                                \
        const float E = __builtin_amdgcn_exp2f(y * -LOG2E);                  \
        const float r1 = 1.0f + E;                                           \
        const float bce2 = __builtin_amdgcn_logf(r1);                        \
        const float ad = bce2 + KBIAS;                                       \
        T0 += bce2;                                                          \
        Tb[0] += (y <= GHM_C1) ? ad : 0.f;                                   \
        Tb[1] += (y <= GHM_C2) ? ad : 0.f;                                   \
        Tb[2] += (y <= GHM_C3) ? ad : 0.f;                                   \
        Tb[3] += (y <= GHM_C4) ? ad : 0.f;                                   \
        Tb[4] += (y <= GHM_C5) ? ad : 0.f;                                   \
        Tb[5] += (y <= GHM_C6) ? ad : 0.f;                                   \
        Tb[6] += (y <= GHM_C7) ? ad : 0.f;                                   \
        Tb[7] += (y <= GHM_C8) ? ad : 0.f;                                   \
        Tb[8] += (y <= GHM_C9) ? ad : 0.f;                                   \
    }

#define GHM_BODY(xv, tv)                                                     \
    {                                                                        \
        GHM_ELEM((xv).x, (tv).x); GHM_ELEM((xv).y, (tv).y);                  \
        GHM_ELEM((xv).z, (tv).z); GHM_ELEM((xv).w, (tv).w);                  \
    }

    for (int tile = blockIdx.x; tile < ntiles; tile += gridDim.x) {
        // Block-contiguous tile: this thread's 2 consecutive float4s per
        // round; rounds advance by 512 float4s (whole block's footprint).
        const float4* __restrict__ p4 =
            reinterpret_cast<const float4*>(pred) + (size_t)tile * (TILE_ELEMS / 4) + tid * 2;
        const int4* __restrict__ t4 =
            reinterpret_cast<const int4*>(target) + (size_t)tile * (TILE_ELEMS / 4) + tid * 2;

        // 2-deep software pipeline over ROUNDS.
        float4 xa0 = p4[0], xa1 = p4[1];
        int4   ta0 = t4[0], ta1 = t4[1];
        for (int r = 1; r < ROUNDS; ++r) {
            const int o = r * (NTHREADS * 2);
            const float4 xb0 = p4[o], xb1 = p4[o + 1];
            const int4   tb0 = t4[o], tb1 = t4[o + 1];
            GHM_BODY(xa0, ta0);
            GHM_BODY(xa1, ta1);
            xa0 = xb0; xa1 = xb1; ta0 = tb0; ta1 = tb1;
        }
        GHM_BODY(xa0, ta0);
        GHM_BODY(xa1, ta1);
    }

    // Tail (n % TILE_ELEMS): last block, thread-strided scalar. Empty at 2^25.
    if (blockIdx.x == gridDim.x - 1) {
        for (int i = ntiles * TILE_ELEMS + tid; i < n; i += NTHREADS) {
            GHM_ELEM(pred[i], target[i]);
        }
    }
#undef GHM_BODY
#undef GHM_ELEM

    // Per-thread decode of the biased accumulators (exact: sum<1024, c<=64).
    float        sums[BINS];
    unsigned int cnts[BINS];
    sums[0] = T0; cnts[0] = 0u;
#pragma unroll
    for (int b = 1; b < BINS; ++b) {
        const float cf = floorf(Tb[b - 1] * (1.0f / KBIAS));
        cnts[b] = (unsigned int)cf;
        sums[b] = Tb[b - 1] - KBIAS * cf;
    }

    // wave reduce -> block combine in LDS -> one global atomic per bin
    __shared__ float        r_T[BINS];
    __shared__ unsigned int r_C[BINS];
    if (tid < BINS) { r_T[tid] = 0.f; r_C[tid] = 0u; }
    __syncthreads();

    const int lane = tid & 63;
#pragma unroll
    for (int b = 0; b < BINS; ++b) {
        const float        v = wave_reduce_add(sums[b]);
        const unsigned int c = (b > 0) ? wave_reduce_addu(cnts[b]) : 0u;
        if (lane == 0) {
            atomicAdd(&r_T[b], v);
            if (b > 0) atomicAdd(&r_C[b], c);
        }
    }
    __syncthreads();

    if (tid < BINS) {
        atomicAdd(&g_T[tid], r_T[tid]);
        atomicAdd(&g_C[tid], r_C[tid]);
    }
}

__global__ void ghm_finalize(const float* __restrict__ g_T,
                             const unsigned int* __restrict__ g_C,
                             const float* __restrict__ acc_sum,
                             float* __restrict__ out, float tot, unsigned int ntot)
{
    if (threadIdx.x == 0 && blockIdx.x == 0) {
        const float LN2 = 0.69314718056f;
        float S[BINS];
        float cntf[BINS];
#pragma unroll
        for (int b = 0; b < BINS; ++b) {
            const float        Tc = g_T[b];
            const float        Tn = (b + 1 < BINS) ? g_T[b + 1] : 0.f;
            const unsigned int Cc = (b == 0) ? ntot : g_C[b];
            const unsigned int Cn = (b + 1 < BINS) ? g_C[b + 1] : 0u;
            S[b]    = (Tc - Tn) * LN2;
            cntf[b] = (float)(Cc - Cn);
        }
        float binw[BINS];
        int nne = 0;
#pragma unroll
        for (int b = 0; b < BINS; ++b) {
            const bool ne = (cntf[b] > 0.0f);
            const float accn = ne ? (0.9f * acc_sum[b] + 0.1f * cntf[b]) : acc_sum[b];
            binw[b] = ne ? (tot / accn) : 0.0f;
            nne += ne ? 1 : 0;
        }
        const float scale = (nne > 0) ? (1.0f / (float)nne) : 1.0f;
        float res = 0.0f;
#pragma unroll
        for (int b = 0; b < BINS; ++b) res += (binw[b] * scale) * S[b];
        out[0] = res / tot;
    }
}

extern "C" void kernel_launch(void* const* d_in, const int* in_sizes, int n_in,
                              void* d_out, int out_size, void* d_ws, size_t ws_size,
                              hipStream_t stream) {
    const float* pred    = (const float*)d_in[0];
    const int*   target  = (const int*)d_in[1];
    const float* acc_sum = (const float*)d_in[2];
    float*       out     = (float*)d_out;

    const int n = in_sizes[0];

    float*        g_T = (float*)d_ws;
    unsigned int* g_C = (unsigned int*)((float*)d_ws + BINS);

    // Zero accumulators every call (ws poisoned once, not re-poisoned).
    hipMemsetAsync(d_ws, 0, 2 * BINS * sizeof(float), stream);

    ghm_pass1<<<2048, NTHREADS, 0, stream>>>(pred, target, g_T, g_C, n);

    const float tot = (float)(n > 1 ? n : 1);
    ghm_finalize<<<1, 64, 0, stream>>>(g_T, g_C, acc_sum, out, tot, (unsigned int)n);
}

// Round 7
// 86.998 us; speedup vs baseline: 1.0368x; 1.0368x over previous
//
#include <hip/hip_runtime.h>

#define BINS 10
#define NTHREADS 256
#define LOG2E 1.44269504f
#define KBIAS 1024.0f
#define TILE_ELEMS (NTHREADS * 64)   // 16384 elements per block-tile
#define ROUNDS 8                     // 8 rounds x 8 elems/thread

// ---------------------------------------------------------------------------
// GHM loss. R7 = R6 (bias-packed staircase, contiguous tiles) + a REAL
// 2-deep load pipeline pinned with sched_barrier(0).
// R6 post-mortem: VGPR=28 proved the compiler collapsed the source pipeline
// into load->vmcnt(0)->compute (4 x ~800cy exposed latency per round, ~30%
// SIMD busy). sched_barrier(0) after the prefetch issue makes instruction
// motion across it illegal -> waitcnt pass emits counted vmcnt(4), keeping
// next round's 4 loads in flight under the current round's compute.
// ---------------------------------------------------------------------------

// c_b = ln((10-b)/b), b=1..9
#define GHM_C1  2.19722458f
#define GHM_C2  1.38629436f
#define GHM_C3  0.84729786f
#define GHM_C4  0.40546511f
#define GHM_C5  0.0f
#define GHM_C6 -0.40546511f
#define GHM_C7 -0.84729786f
#define GHM_C8 -1.38629436f
#define GHM_C9 -2.19722458f

__device__ __forceinline__ float wave_reduce_add(float v) {
#pragma unroll
    for (int off = 32; off > 0; off >>= 1) v += __shfl_down(v, off, 64);
    return v;
}
__device__ __forceinline__ unsigned int wave_reduce_addu(unsigned int v) {
#pragma unroll
    for (int off = 32; off > 0; off >>= 1) v += __shfl_down((int)v, off, 64);
    return v;
}

__global__ __launch_bounds__(NTHREADS, 6) void ghm_pass1(
    const float* __restrict__ pred, const int* __restrict__ target,
    float* __restrict__ g_T,            // [BINS] cumulative bce2 sums
    unsigned int* __restrict__ g_C,     // [BINS] cumulative counts (1..9 used)
    int n)
{
    float T0 = 0.f;
    float Tb[9];
#pragma unroll
    for (int b = 0; b < 9; ++b) Tb[b] = 0.f;

    const int tid    = threadIdx.x;
    const int ntiles = n / TILE_ELEMS;

#define GHM_ELEM(x_, t_)                                                     \
    {                                                                        \
        const float x = (x_);                                                \
        const float y = ((t_) != 0) ? x : -x;                                \
        const float E = __builtin_amdgcn_exp2f(y * -LOG2E);                  \
        const float bce2 = __builtin_amdgcn_logf(1.0f + E);                  \
        const float ad = bce2 + KBIAS;                                       \
        T0 += bce2;                                                          \
        Tb[0] += (y <= GHM_C1) ? ad : 0.f;                                   \
        Tb[1] += (y <= GHM_C2) ? ad : 0.f;                                   \
        Tb[2] += (y <= GHM_C3) ? ad : 0.f;                                   \
        Tb[3] += (y <= GHM_C4) ? ad : 0.f;                                   \
        Tb[4] += (y <= GHM_C5) ? ad : 0.f;                                   \
        Tb[5] += (y <= GHM_C6) ? ad : 0.f;                                   \
        Tb[6] += (y <= GHM_C7) ? ad : 0.f;                                   \
        Tb[7] += (y <= GHM_C8) ? ad : 0.f;                                   \
        Tb[8] += (y <= GHM_C9) ? ad : 0.f;                                   \
    }

#define GHM_BODY(xv, tv)                                                     \
    {                                                                        \
        GHM_ELEM((xv).x, (tv).x); GHM_ELEM((xv).y, (tv).y);                  \
        GHM_ELEM((xv).z, (tv).z); GHM_ELEM((xv).w, (tv).w);                  \
    }

    for (int tile = blockIdx.x; tile < ntiles; tile += gridDim.x) {
        const float4* __restrict__ p4 =
            reinterpret_cast<const float4*>(pred) + (size_t)tile * (TILE_ELEMS / 4) + tid * 2;
        const int4* __restrict__ t4 =
            reinterpret_cast<const int4*>(target) + (size_t)tile * (TILE_ELEMS / 4) + tid * 2;

        // ---- pinned 2-deep pipeline ----
        float4 xa0 = p4[0], xa1 = p4[1];
        int4   ta0 = t4[0], ta1 = t4[1];
        __builtin_amdgcn_sched_barrier(0);   // r0 loads stay above everything
#pragma unroll 1
        for (int r = 1; r < ROUNDS; ++r) {
            const int o = r * (NTHREADS * 2);
            const float4 xb0 = p4[o], xb1 = p4[o + 1];
            const int4   tb0 = t4[o], tb1 = t4[o + 1];
            __builtin_amdgcn_sched_barrier(0);   // loads(r) pinned above compute(r-1)
            GHM_BODY(xa0, ta0);
            GHM_BODY(xa1, ta1);
            __builtin_amdgcn_sched_barrier(0);   // compute(r-1) cannot sink below rotate
            xa0 = xb0; xa1 = xb1; ta0 = tb0; ta1 = tb1;
        }
        GHM_BODY(xa0, ta0);
        GHM_BODY(xa1, ta1);
    }

    // Tail (n % TILE_ELEMS): empty for N=2^25, kept for generality.
    if (blockIdx.x == gridDim.x - 1) {
        for (int i = ntiles * TILE_ELEMS + tid; i < n; i += NTHREADS) {
            GHM_ELEM(pred[i], target[i]);
        }
    }
#undef GHM_BODY
#undef GHM_ELEM

    // Per-thread decode of biased accumulators (exact: sum<1024, cnt<=64).
    float        sums[BINS];
    unsigned int cnts[BINS];
    sums[0] = T0; cnts[0] = 0u;
#pragma unroll
    for (int b = 1; b < BINS; ++b) {
        const float cf = floorf(Tb[b - 1] * (1.0f / KBIAS));
        cnts[b] = (unsigned int)cf;
        sums[b] = Tb[b - 1] - KBIAS * cf;
    }

    __shared__ float        r_T[BINS];
    __shared__ unsigned int r_C[BINS];
    if (tid < BINS) { r_T[tid] = 0.f; r_C[tid] = 0u; }
    __syncthreads();

    const int lane = tid & 63;
#pragma unroll
    for (int b = 0; b < BINS; ++b) {
        const float        v = wave_reduce_add(sums[b]);
        const unsigned int c = (b > 0) ? wave_reduce_addu(cnts[b]) : 0u;
        if (lane == 0) {
            atomicAdd(&r_T[b], v);
            if (b > 0) atomicAdd(&r_C[b], c);
        }
    }
    __syncthreads();

    if (tid < BINS) {
        atomicAdd(&g_T[tid], r_T[tid]);
        atomicAdd(&g_C[tid], r_C[tid]);
    }
}

__global__ void ghm_finalize(const float* __restrict__ g_T,
                             const unsigned int* __restrict__ g_C,
                             const float* __restrict__ acc_sum,
                             float* __restrict__ out, float tot, unsigned int ntot)
{
    if (threadIdx.x == 0 && blockIdx.x == 0) {
        const float LN2 = 0.69314718056f;
        float S[BINS];
        float cntf[BINS];
#pragma unroll
        for (int b = 0; b < BINS; ++b) {
            const float        Tc = g_T[b];
            const float        Tn = (b + 1 < BINS) ? g_T[b + 1] : 0.f;
            const unsigned int Cc = (b == 0) ? ntot : g_C[b];
            const unsigned int Cn = (b + 1 < BINS) ? g_C[b + 1] : 0u;
            S[b]    = (Tc - Tn) * LN2;
            cntf[b] = (float)(Cc - Cn);
        }
        float binw[BINS];
        int nne = 0;
#pragma unroll
        for (int b = 0; b < BINS; ++b) {
            const bool ne = (cntf[b] > 0.0f);
            const float accn = ne ? (0.9f * acc_sum[b] + 0.1f * cntf[b]) : acc_sum[b];
            binw[b] = ne ? (tot / accn) : 0.0f;
            nne += ne ? 1 : 0;
        }
        const float scale = (nne > 0) ? (1.0f / (float)nne) : 1.0f;
        float res = 0.0f;
#pragma unroll
        for (int b = 0; b < BINS; ++b) res += (binw[b] * scale) * S[b];
        out[0] = res / tot;
    }
}

extern "C" void kernel_launch(void* const* d_in, const int* in_sizes, int n_in,
                              void* d_out, int out_size, void* d_ws, size_t ws_size,
                              hipStream_t stream) {
    const float* pred    = (const float*)d_in[0];
    const int*   target  = (const int*)d_in[1];
    const float* acc_sum = (const float*)d_in[2];
    float*       out     = (float*)d_out;

    const int n = in_sizes[0];

    float*        g_T = (float*)d_ws;
    unsigned int* g_C = (unsigned int*)((float*)d_ws + BINS);

    hipMemsetAsync(d_ws, 0, 2 * BINS * sizeof(float), stream);

    ghm_pass1<<<2048, NTHREADS, 0, stream>>>(pred, target, g_T, g_C, n);

    const float tot = (float)(n > 1 ? n : 1);
    ghm_finalize<<<1, 64, 0, stream>>>(g_T, g_C, acc_sum, out, tot, (unsigned int)n);
}

// Round 8
// 84.070 us; speedup vs baseline: 1.0729x; 1.0348x over previous
//
#include <hip/hip_runtime.h>

#define BINS 10
#define NTHREADS 256
#define LOG2E 1.44269504f
#define KBIAS 1024.0f
#define TILE_ELEMS (NTHREADS * 64)     // 16384 elems per block-tile
#define ROUND_BYTES (NTHREADS * 16)    // 4096 B per stream per round

// ---------------------------------------------------------------------------
// GHM loss. R8: inline-asm load pipeline with counted vmcnt (AITER pattern).
// R7 post-mortem: VGPR=32 proved sched_barrier alone cannot keep a register
// pipeline alive; compiler waitcnt still serialized loads. Fix: ALL streaming
// loads are inline-asm global_load_dwordx4 (pred+target share one voffset,
// SGPR base pair); the ONLY waits in the loop are our asm s_waitcnt vmcnt(6)
// (steady state: 6 of 8 loads in flight) + sched_barrier(0) per rule #18.
// Core math in log2 domain: w = +-x*log2e, staircase consts log2((10-b)/b),
// bce2 = log2(1+exp2(-w)), count bias-packed (+1024) into the same accum.
// ---------------------------------------------------------------------------

typedef float        f32x4 __attribute__((ext_vector_type(4)));
typedef unsigned int u32x4 __attribute__((ext_vector_type(4)));

__device__ __forceinline__ float wave_reduce_add(float v) {
#pragma unroll
    for (int off = 32; off > 0; off >>= 1) v += __shfl_down(v, off, 64);
    return v;
}
__device__ __forceinline__ unsigned int wave_reduce_addu(unsigned int v) {
#pragma unroll
    for (int off = 32; off > 0; off >>= 1) v += __shfl_down((int)v, off, 64);
    return v;
}

__global__ __launch_bounds__(NTHREADS, 6) void ghm_pass1(
    const float* __restrict__ pred, const int* __restrict__ target,
    float* __restrict__ g_T,            // [BINS] cumulative bce2 sums
    unsigned int* __restrict__ g_C,     // [BINS] cumulative counts (1..9 used)
    int n)
{
    float T0 = 0.f;
    float Tb[9];
#pragma unroll
    for (int b = 0; b < 9; ++b) Tb[b] = 0.f;

    const int tid    = threadIdx.x;
    const int ntiles = n / TILE_ELEMS;

    // staircase constants: log2((10-b)/b), b=1..9
#define GHM_ELEM(x_, tu_)                                                   \
    {                                                                       \
        const float z = (x_) * LOG2E;                                       \
        const float w = ((tu_) != 0u) ? z : -z;                             \
        const float E = __builtin_amdgcn_exp2f(-w);                         \
        const float bce2 = __builtin_amdgcn_logf(1.0f + E);                 \
        const float ad = bce2 + KBIAS;                                      \
        T0 += bce2;                                                         \
        Tb[0] += (w <=  3.16992500f) ? ad : 0.f;                            \
        Tb[1] += (w <=  2.0f)        ? ad : 0.f;                            \
        Tb[2] += (w <=  1.22239242f) ? ad : 0.f;                            \
        Tb[3] += (w <=  0.58496250f) ? ad : 0.f;                            \
        Tb[4] += (w <=  0.0f)        ? ad : 0.f;                            \
        Tb[5] += (w <= -0.58496250f) ? ad : 0.f;                            \
        Tb[6] += (w <= -1.22239242f) ? ad : 0.f;                            \
        Tb[7] += (w <= -2.0f)        ? ad : 0.f;                            \
        Tb[8] += (w <= -3.16992500f) ? ad : 0.f;                            \
    }

#define COMPUTE(X, Tv)                                                      \
    {                                                                       \
        GHM_ELEM((X)[0], (Tv)[0]); GHM_ELEM((X)[1], (Tv)[1]);               \
        GHM_ELEM((X)[2], (Tv)[2]); GHM_ELEM((X)[3], (Tv)[3]);               \
    }

    // One asm block = 2 loads (pred, target), shared 32-bit voffset, SGPR
    // bases. "=&v" early-clobber so outputs can't alias the address regs.
#define ISSUE(X, Tv, off)                                                   \
    asm volatile("global_load_dwordx4 %0, %2, %3\n\t"                       \
                 "global_load_dwordx4 %1, %2, %4"                           \
                 : "=&v"(X), "=&v"(Tv)                                      \
                 : "v"(off), "s"(pred), "s"(target))

    // Counted wait + scheduling fence (rule #18: compute must not hoist).
#define VWAIT(nn)                                                           \
    do { asm volatile("s_waitcnt vmcnt(" #nn ")" ::: "memory");             \
         __builtin_amdgcn_sched_barrier(0); } while (0)

    if (blockIdx.x < (unsigned)ntiles) {
        unsigned int voff = (unsigned)blockIdx.x * (TILE_ELEMS * 4u)
                          + (unsigned)tid * 16u;
        f32x4 x0, x1, x2, x3;
        u32x4 t0, t1, t2, t3;

        // prologue: 4 rounds in flight (8 loads)
        ISSUE(x0, t0, voff); voff += ROUND_BYTES;
        ISSUE(x1, t1, voff); voff += ROUND_BYTES;
        ISSUE(x2, t2, voff); voff += ROUND_BYTES;
        ISSUE(x3, t3, voff); voff += ROUND_BYTES;

#pragma unroll 1
        for (int g = 0; g < 3; ++g) {
            VWAIT(6); COMPUTE(x0, t0); ISSUE(x0, t0, voff); voff += ROUND_BYTES;
            VWAIT(6); COMPUTE(x1, t1); ISSUE(x1, t1, voff); voff += ROUND_BYTES;
            VWAIT(6); COMPUTE(x2, t2); ISSUE(x2, t2, voff); voff += ROUND_BYTES;
            VWAIT(6); COMPUTE(x3, t3); ISSUE(x3, t3, voff); voff += ROUND_BYTES;
        }
        // epilogue: drain
        VWAIT(6); COMPUTE(x0, t0);
        VWAIT(4); COMPUTE(x1, t1);
        VWAIT(2); COMPUTE(x2, t2);
        VWAIT(0); COMPUTE(x3, t3);
    }

    // Tail (n % TILE_ELEMS), last block, plain scalar loads. Empty at 2^25.
    if (blockIdx.x == gridDim.x - 1) {
        for (int i = ntiles * TILE_ELEMS + tid; i < n; i += NTHREADS) {
            const float xs = pred[i];
            const unsigned int tu = (unsigned int)target[i];
            GHM_ELEM(xs, tu);
        }
    }
#undef ISSUE
#undef VWAIT
#undef COMPUTE
#undef GHM_ELEM

    // Per-thread decode of biased accumulators (exact: sum<1024, cnt<=64).
    float        sums[BINS];
    unsigned int cnts[BINS];
    sums[0] = T0; cnts[0] = 0u;
#pragma unroll
    for (int b = 1; b < BINS; ++b) {
        const float cf = floorf(Tb[b - 1] * (1.0f / KBIAS));
        cnts[b] = (unsigned int)cf;
        sums[b] = Tb[b - 1] - KBIAS * cf;
    }

    __shared__ float        r_T[BINS];
    __shared__ unsigned int r_C[BINS];
    if (tid < BINS) { r_T[tid] = 0.f; r_C[tid] = 0u; }
    __syncthreads();

    const int lane = tid & 63;
#pragma unroll
    for (int b = 0; b < BINS; ++b) {
        const float        v = wave_reduce_add(sums[b]);
        const unsigned int c = (b > 0) ? wave_reduce_addu(cnts[b]) : 0u;
        if (lane == 0) {
            atomicAdd(&r_T[b], v);
            if (b > 0) atomicAdd(&r_C[b], c);
        }
    }
    __syncthreads();

    if (tid < BINS) {
        atomicAdd(&g_T[tid], r_T[tid]);
        atomicAdd(&g_C[tid], r_C[tid]);
    }
}

__global__ void ghm_finalize(const float* __restrict__ g_T,
                             const unsigned int* __restrict__ g_C,
                             const float* __restrict__ acc_sum,
                             float* __restrict__ out, float tot, unsigned int ntot)
{
    if (threadIdx.x == 0 && blockIdx.x == 0) {
        const float LN2 = 0.69314718056f;
        float S[BINS];
        float cntf[BINS];
#pragma unroll
        for (int b = 0; b < BINS; ++b) {
            const float        Tc = g_T[b];
            const float        Tn = (b + 1 < BINS) ? g_T[b + 1] : 0.f;
            const unsigned int Cc = (b == 0) ? ntot : g_C[b];
            const unsigned int Cn = (b + 1 < BINS) ? g_C[b + 1] : 0u;
            S[b]    = (Tc - Tn) * LN2;
            cntf[b] = (float)(Cc - Cn);
        }
        float binw[BINS];
        int nne = 0;
#pragma unroll
        for (int b = 0; b < BINS; ++b) {
            const bool ne = (cntf[b] > 0.0f);
            const float accn = ne ? (0.9f * acc_sum[b] + 0.1f * cntf[b]) : acc_sum[b];
            binw[b] = ne ? (tot / accn) : 0.0f;
            nne += ne ? 1 : 0;
        }
        const float scale = (nne > 0) ? (1.0f / (float)nne) : 1.0f;
        float res = 0.0f;
#pragma unroll
        for (int b = 0; b < BINS; ++b) res += (binw[b] * scale) * S[b];
        out[0] = res / tot;
    }
}

extern "C" void kernel_launch(void* const* d_in, const int* in_sizes, int n_in,
                              void* d_out, int out_size, void* d_ws, size_t ws_size,
                              hipStream_t stream) {
    const float* pred    = (const float*)d_in[0];
    const int*   target  = (const int*)d_in[1];
    const float* acc_sum = (const float*)d_in[2];
    float*       out     = (float*)d_out;

    const int n = in_sizes[0];
    const int ntiles = n / TILE_ELEMS;
    const int grid = (ntiles > 0) ? ntiles : 1;

    float*        g_T = (float*)d_ws;
    unsigned int* g_C = (unsigned int*)((float*)d_ws + BINS);

    hipMemsetAsync(d_ws, 0, 2 * BINS * sizeof(float), stream);

    ghm_pass1<<<grid, NTHREADS, 0, stream>>>(pred, target, g_T, g_C, n);

    const float tot = (float)(n > 1 ? n : 1);
    ghm_finalize<<<1, 64, 0, stream>>>(g_T, g_C, acc_sum, out, tot, (unsigned int)n);
}